// Round 4
// baseline (233.943 us; speedup 1.0000x reference)
//
#include <hip/hip_runtime.h>
#include <hip/hip_bf16.h>

typedef __attribute__((ext_vector_type(8))) __bf16 bf16x8;
typedef __attribute__((ext_vector_type(8))) short short8;
typedef __attribute__((ext_vector_type(4))) float f32x4;
typedef __attribute__((ext_vector_type(16))) float f32x16;
typedef __attribute__((ext_vector_type(4))) short sh4;

typedef __attribute__((address_space(1))) void GVoid;
typedef __attribute__((address_space(3))) void LVoid;

#define NEGBIG (-1e30f)
#define SCL 0.18033688011112042f   // 0.125 * log2(e): folded into Q at GEMM1 epilogue

constexpr int TT = 2048, CC = 1024, HH = 16, DD = 64, C3 = 3072;

__device__ __forceinline__ unsigned short f2bf(float f) {   // RNE
  unsigned int i = __float_as_uint(f);
  return (unsigned short)((i + 0x7FFFu + ((i >> 16) & 1u)) >> 16);
}
__device__ __forceinline__ void async16(const void* g, void* l) {
  __builtin_amdgcn_global_load_lds((GVoid*)g, (LVoid*)l, 16, 0, 0);
}

// ---------- pre-pass: fp32 -> bf16 elementwise convert ----------
__global__ __launch_bounds__(256) void cvt_bf16(
    const float* __restrict__ in, unsigned short* __restrict__ out, int n8)
{
  const int i = blockIdx.x * 256 + threadIdx.x;
  if (i >= n8) return;
  const float* p = in + (size_t)i * 8;
  f32x4 a = *(const f32x4*)p, b = *(const f32x4*)(p + 4);
  sh4 r0, r1;
  ((unsigned short*)&r0)[0] = f2bf(a[0]); ((unsigned short*)&r0)[1] = f2bf(a[1]);
  ((unsigned short*)&r0)[2] = f2bf(a[2]); ((unsigned short*)&r0)[3] = f2bf(a[3]);
  ((unsigned short*)&r1)[0] = f2bf(b[0]); ((unsigned short*)&r1)[1] = f2bf(b[1]);
  ((unsigned short*)&r1)[2] = f2bf(b[2]); ((unsigned short*)&r1)[3] = f2bf(b[3]);
  *(sh4*)(out + (size_t)i * 8) = r0;
  *(sh4*)(out + (size_t)i * 8 + 4) = r1;
}

// ---------- pre-pass: transpose + convert: fp32 in[R][Cd] -> bf16 out[Cd][R] ----------
__global__ __launch_bounds__(256) void transpose_cvt(
    const float* __restrict__ in, unsigned short* __restrict__ out, int R, int Cd)
{
  __shared__ __align__(16) unsigned short tile[64 * 72];
  const int r0 = blockIdx.y * 64, c0 = blockIdx.x * 64;
  const int tid = threadIdx.x;
#pragma unroll
  for (int r = 0; r < 2; ++r) {
    const int elem = r * 2048 + tid * 8;
    const int ii = elem >> 6, jj = elem & 63;
    const float* p = in + (size_t)(r0 + ii) * Cd + c0 + jj;
    f32x4 a = *(const f32x4*)p, b = *(const f32x4*)(p + 4);
    short8 v;
    ((unsigned short*)&v)[0] = f2bf(a[0]); ((unsigned short*)&v)[1] = f2bf(a[1]);
    ((unsigned short*)&v)[2] = f2bf(a[2]); ((unsigned short*)&v)[3] = f2bf(a[3]);
    ((unsigned short*)&v)[4] = f2bf(b[0]); ((unsigned short*)&v)[5] = f2bf(b[1]);
    ((unsigned short*)&v)[6] = f2bf(b[2]); ((unsigned short*)&v)[7] = f2bf(b[3]);
    *(short8*)&tile[ii * 72 + jj] = v;
  }
  __syncthreads();
#pragma unroll
  for (int r = 0; r < 2; ++r) {
    const int elem = r * 2048 + tid * 8;
    const int jj = elem >> 6, ii0 = elem & 63;
    short8 v;
#pragma unroll
    for (int e = 0; e < 8; ++e) ((unsigned short*)&v)[e] = tile[(ii0 + e) * 72 + jj];
    *(short8*)&out[(size_t)(c0 + jj) * R + r0 + ii0] = v;
  }
}

// ---------------- GEMM (m97 structure) ----------------
template <int MODE>
__global__ __launch_bounds__(256) void gemm_bt(
    const unsigned short* __restrict__ A,
    const unsigned short* __restrict__ Bt,
    const float* __restrict__ bias,
    void* __restrict__ Cp, unsigned short* __restrict__ Vt,
    int M, int N, int K, int lda)
{
  __shared__ __align__(16) unsigned short sA[128 * 32];
  __shared__ __align__(16) unsigned short sB[128 * 32];
  const int tid = threadIdx.x;
  const int w = tid >> 6, l = tid & 63, ln = l & 15, quad = l >> 4;
  const int wm = w >> 1, wn = w & 1;
  const int m0 = blockIdx.y * 128, n0 = blockIdx.x * 128;
  f32x4 acc[4][4] = {};

  for (int k0 = 0; k0 < K; k0 += 32) {
    __syncthreads();
#pragma unroll
    for (int r = 0; r < 2; ++r) {
      const int elem = r * 2048 + tid * 8;
      const int ar = elem >> 5, ac = elem & 31;
      async16(A  + (size_t)(m0 + ar) * lda + k0 + ac, sA + r * 2048 + w * 512);
      async16(Bt + (size_t)(n0 + ar) * K   + k0 + ac, sB + r * 2048 + w * 512);
    }
    __syncthreads();

    bf16x8 af[4], bfr[4];
#pragma unroll
    for (int i = 0; i < 4; i++)
      af[i] = *(const bf16x8*)&sA[(wm * 64 + i * 16 + ln) * 32 + quad * 8];
#pragma unroll
    for (int j = 0; j < 4; j++)
      bfr[j] = *(const bf16x8*)&sB[(wn * 64 + j * 16 + ln) * 32 + quad * 8];
#pragma unroll
    for (int i = 0; i < 4; i++)
#pragma unroll
      for (int j = 0; j < 4; j++)
        acc[i][j] = __builtin_amdgcn_mfma_f32_16x16x32_bf16(af[i], bfr[j], acc[i][j], 0, 0, 0);
  }

  float bj[4];
#pragma unroll
  for (int j = 0; j < 4; j++) bj[j] = bias[n0 + wn * 64 + j * 16 + ln];

#pragma unroll
  for (int i = 0; i < 4; i++)
#pragma unroll
    for (int g = 0; g < 4; ++g) {
      const int gm = m0 + wm * 64 + i * 16 + quad * 4 + g;
#pragma unroll
      for (int j = 0; j < 4; j++) {
        const int gn = n0 + wn * 64 + j * 16 + ln;
        float v = acc[i][j][g] + bj[j];
        if (MODE == 0) {
          if (gn < 2048) {
            if (gn < 1024) v *= SCL;       // fold softmax scale into Q (pre-round: free)
            ((unsigned short*)Cp)[(size_t)gm * 2048 + gn] = f2bf(v);
          } else {
            const int hh = (gn >> 6) & 15, dd = gn & 63;
            const int bb = gm >> 11, t = gm & 2047;
            Vt[((size_t)((bb * HH + hh) * DD + dd)) * TT + t] = f2bf(v);
          }
        } else {
          ((float*)Cp)[(size_t)gm * N + gn] = v;
        }
      }
    }
}

// ---------------- Flash attention (causal), D=64, per-wave independent ----------------
// NO LDS staging, NO per-iteration barriers (rounds 0-3 evidence: barrier-lockstep
// + 1-2 waves/SIMD left every pipe <50% busy; removing LDS traffic alone didn't help).
// Each WAVE owns a 32-row q-strip; K/V fragments loaded straight from global (L2)
// into registers, 16x dwordx4 per iter, base+imm addressing. 32x32 S^T MFMA +
// in-register cvt_pk/permlane32_swap softmax (round-3-verified). STATIC softmax
// (additive partials), so a TEAM of 2 waves splits the strip by k-tile PARITY and
// merges once at the end via 16KB LDS + one barrier -> max wave job 17 iters, not 34.
// Block = 2 teams (4 waves, 256 thr), launch_bounds(256,2) -> 2 blocks/CU = 2
// independent waves/SIMD. Grid 1024 = 2x oversubscribed, strips DESC (LPT backfill);
// blockIdx&7 selects a 4-bh class (XCD-aligned round-robin) -> per-XCD K/V working
// set ~2MB < 4MB L2.
__global__ __launch_bounds__(256, 2) void attn_pw(
    unsigned short* __restrict__ QK, const unsigned short* __restrict__ Vt)
{
  __shared__ float Ox[2][2][16][64];                        // [team][dg][reg][lane]
  __shared__ float Lx[2][64];
  const int Bk = blockIdx.x;
  const int xcd = Bk & 7, rr_ = Bk >> 3;
  const int s = 63 - (rr_ >> 1), j = rr_ & 1;               // strip (desc), bh-pair
  const int tid = threadIdx.x;
  const int team = tid >> 7, par = (tid >> 6) & 1, l = tid & 63;
  const int c = l & 31, h2 = l >> 5;
  const int bh = xcd * 4 + 2 * j + team;
  const int b = bh >> 4, h = bh & 15;
  unsigned short*       Qp = QK + (size_t)b * TT * 2048 + h * DD;
  const unsigned short* Kp = QK + (size_t)b * TT * 2048 + CC + h * DD;
  const unsigned short* Vh = Vt + (size_t)bh * DD * TT;

  const int qbase = s * 32;
  const int qm = qbase + c - 4 * h2;                        // mask helper
  const int kb_last = s >> 1;

  bf16x8 qv[4];
#pragma unroll
  for (int ds = 0; ds < 4; ++ds)                            // Q B-operand frags
    qv[ds] = *(const bf16x8*)&Qp[(size_t)(qbase + c) * 2048 + ds * 16 + h2 * 8];

  f32x16 oacc[2] = {};
  float ls0 = 0.0f, ls1 = 0.0f;

  for (int kb = par; kb <= kb_last; kb += 2) {
    // ---- issue all 16 global loads up front (K first: QK waits only on K; ----
    // ---- V latency hides under softmax VALU)                              ----
    const unsigned short* pk = Kp + (size_t)(kb * 64 + c) * 2048 + h2 * 8;
    bf16x8 kf[2][4];
#pragma unroll
    for (int kg = 0; kg < 2; ++kg)
#pragma unroll
      for (int ds = 0; ds < 4; ++ds)
        kf[kg][ds] = *(const bf16x8*)(pk + (size_t)kg * 32 * 2048 + ds * 16);
    const unsigned short* pv = Vh + (size_t)c * TT + kb * 64 + h2 * 8;
    bf16x8 vf[2][4];
#pragma unroll
    for (int dg = 0; dg < 2; ++dg)
#pragma unroll
      for (int ks = 0; ks < 4; ++ks)
        vf[dg][ks] = *(const bf16x8*)(pv + (size_t)dg * 32 * TT + ks * 16);

    // ---- S^T(kb) = K * Q^T ----
    f32x16 sacc[2];
#pragma unroll
    for (int kg = 0; kg < 2; ++kg) {
      f32x16 sa = {};
#pragma unroll
      for (int ds = 0; ds < 4; ++ds)
        sa = __builtin_amdgcn_mfma_f32_32x32x16_bf16(kf[kg][ds], qv[ds], sa, 0, 0, 0);
      sacc[kg] = sa;
    }

    // ---- softmax (static, log2 domain, raw v_exp_f32) ----
    const bool need_mask = (kb == kb_last);
    float pe[2][16];
#pragma unroll
    for (int kg = 0; kg < 2; ++kg)
#pragma unroll
      for (int rr = 0; rr < 16; ++rr) {
        float sv = sacc[kg][rr];
        if (need_mask) {
          const int krel = kb * 64 + kg * 32 + (rr & 3) + 8 * (rr >> 2);
          if (krel > qm) sv = NEGBIG;                       // key > q -> masked
        }
        float e;
        asm("v_exp_f32 %0, %1" : "=v"(e) : "v"(sv));        // 2^sv; 2^-1e30 = 0
        pe[kg][rr] = e;
        if (rr & 1) ls1 += e; else ls0 += e;
      }
    // pack P^T pairs to bf16 and redistribute to PV A-fragments (round-3-verified)
    unsigned W0[2][4], W1[2][4];
#pragma unroll
    for (int kg = 0; kg < 2; ++kg)
#pragma unroll
      for (int r4 = 0; r4 < 4; ++r4) {
        asm("v_cvt_pk_bf16_f32 %0, %1, %2"
            : "=v"(W0[kg][r4]) : "v"(pe[kg][4 * r4 + 0]), "v"(pe[kg][4 * r4 + 1]));
        asm("v_cvt_pk_bf16_f32 %0, %1, %2"
            : "=v"(W1[kg][r4]) : "v"(pe[kg][4 * r4 + 2]), "v"(pe[kg][4 * r4 + 3]));
      }
    bf16x8 pA[4];
#pragma unroll
    for (int ks = 0; ks < 4; ++ks) {
      const int kg = ks >> 1, sel = ks & 1;
      unsigned a0 = W0[kg][2 * sel], b0 = W0[kg][2 * sel + 1];
      unsigned a1 = W1[kg][2 * sel], b1 = W1[kg][2 * sel + 1];
      asm("v_permlane32_swap_b32 %0, %1" : "+v"(a0), "+v"(b0));
      asm("v_permlane32_swap_b32 %0, %1" : "+v"(a1), "+v"(b1));
      unsigned wds[4] = {a0, a1, b0, b1};                   // keys e01,e23,e45,e67
      pA[ks] = *(const bf16x8*)wds;
    }

    // ---- PV(kb) ----
#pragma unroll
    for (int dg = 0; dg < 2; ++dg)
#pragma unroll
      for (int ks = 0; ks < 4; ++ks)
        oacc[dg] = __builtin_amdgcn_mfma_f32_32x32x16_bf16(pA[ks], vf[dg][ks], oacc[dg], 0, 0, 0);
  }

  // ---- team merge (parity partials are purely additive under static softmax) ----
  float lw = ls0 + ls1;
  lw += __shfl_xor(lw, 32);                                 // l partial for q = lane&31
  if (par == 1) {
#pragma unroll
    for (int dg = 0; dg < 2; ++dg)
#pragma unroll
      for (int rr = 0; rr < 16; ++rr) Ox[team][dg][rr][l] = oacc[dg][rr];
    Lx[team][l] = lw;
  }
  __syncthreads();                                          // once per strip
  if (par == 0) {
    const float inv = 1.0f / (lw + Lx[team][l]);
#pragma unroll
    for (int dg = 0; dg < 2; ++dg)
#pragma unroll
      for (int rr = 0; rr < 16; ++rr) oacc[dg][rr] += Ox[team][dg][rr][l];
#pragma unroll
    for (int rr = 0; rr < 16; ++rr) {
      const int q_rel = (rr & 3) + 8 * (rr >> 2) + 4 * h2;
      const float iq = __shfl(inv, q_rel);
      const size_t trow = qbase + q_rel;
#pragma unroll
      for (int dg = 0; dg < 2; ++dg)
        Qp[trow * 2048 + dg * 32 + c] = f2bf(oacc[dg][rr] * iq);
    }
  }
}

extern "C" void kernel_launch(void* const* d_in, const int* in_sizes, int n_in,
                              void* d_out, int out_size, void* d_ws, size_t ws_size,
                              hipStream_t stream)
{
  (void)in_sizes; (void)n_in; (void)out_size; (void)ws_size;
  const float* x     = (const float*)d_in[0];   // [B,T,C] fp32
  const float* Wqkv  = (const float*)d_in[1];   // [C,3C]
  const float* bqkv  = (const float*)d_in[2];   // [3C]
  const float* Wproj = (const float*)d_in[3];   // [C,C]
  const float* bproj = (const float*)d_in[4];   // [C]

  unsigned short* QK     = (unsigned short*)d_ws;            // [4096][2048] bf16, 16 MB
  unsigned short* WqkvT  = QK + (size_t)4096 * 2048;         // [3072][1024] bf16, 6 MB
  unsigned short* WprojT = WqkvT;                            // aliases (after GEMM1)
  unsigned short* Vt = (unsigned short*)d_out;               // scratch in d_out, 8 MB
  unsigned short* xb = Vt + (size_t)32 * 64 * 2048;          // scratch in d_out, 8 MB

  cvt_bf16<<<dim3(4096 * 1024 / 8 / 256), 256, 0, stream>>>(x, xb, 4096 * 1024 / 8);
  transpose_cvt<<<dim3(C3 / 64, CC / 64), 256, 0, stream>>>(Wqkv, WqkvT, CC, C3);
  gemm_bt<0><<<dim3(C3 / 128, 4096 / 128), 256, 0, stream>>>(
      xb, WqkvT, bqkv, QK, Vt, 4096, C3, CC, CC);
  transpose_cvt<<<dim3(CC / 64, CC / 64), 256, 0, stream>>>(Wproj, WprojT, CC, CC);
  attn_pw<<<dim3(1024), 256, 0, stream>>>(QK, Vt);
  gemm_bt<1><<<dim3(CC / 128, 4096 / 128), 256, 0, stream>>>(
      QK, WprojT, bproj, d_out, nullptr, 4096, CC, CC, 2048);
}

// Round 5
// 198.149 us; speedup vs baseline: 1.1806x; 1.1806x over previous
//
#include <hip/hip_runtime.h>
#include <hip/hip_bf16.h>

typedef __attribute__((ext_vector_type(8))) __bf16 bf16x8;
typedef __attribute__((ext_vector_type(8))) short short8;
typedef __attribute__((ext_vector_type(4))) float f32x4;
typedef __attribute__((ext_vector_type(4))) short sh4;

typedef __attribute__((address_space(1))) void GVoid;
typedef __attribute__((address_space(3))) void LVoid;

#define NEGBIG (-1e30f)
#define SCL 0.18033688011112042f   // 0.125 * log2(e): folded into Q at GEMM1 epilogue

constexpr int TT = 2048, CC = 1024, HH = 16, DD = 64, C3 = 3072;

__device__ __forceinline__ unsigned short f2bf(float f) {   // RNE
  unsigned int i = __float_as_uint(f);
  return (unsigned short)((i + 0x7FFFu + ((i >> 16) & 1u)) >> 16);
}
__device__ __forceinline__ unsigned short f2bf_tr(float f) {  // truncate (P only)
  return (unsigned short)(__float_as_uint(f) >> 16);
}
__device__ __forceinline__ void async16(const void* g, void* l) {
  __builtin_amdgcn_global_load_lds((GVoid*)g, (LVoid*)l, 16, 0, 0);
}

// ---------- pre-pass: fp32 -> bf16 elementwise convert ----------
__global__ __launch_bounds__(256) void cvt_bf16(
    const float* __restrict__ in, unsigned short* __restrict__ out, int n8)
{
  const int i = blockIdx.x * 256 + threadIdx.x;
  if (i >= n8) return;
  const float* p = in + (size_t)i * 8;
  f32x4 a = *(const f32x4*)p, b = *(const f32x4*)(p + 4);
  sh4 r0, r1;
  ((unsigned short*)&r0)[0] = f2bf(a[0]); ((unsigned short*)&r0)[1] = f2bf(a[1]);
  ((unsigned short*)&r0)[2] = f2bf(a[2]); ((unsigned short*)&r0)[3] = f2bf(a[3]);
  ((unsigned short*)&r1)[0] = f2bf(b[0]); ((unsigned short*)&r1)[1] = f2bf(b[1]);
  ((unsigned short*)&r1)[2] = f2bf(b[2]); ((unsigned short*)&r1)[3] = f2bf(b[3]);
  *(sh4*)(out + (size_t)i * 8) = r0;
  *(sh4*)(out + (size_t)i * 8 + 4) = r1;
}

// ---------- pre-pass: transpose + convert: fp32 in[R][Cd] -> bf16 out[Cd][R] ----------
__global__ __launch_bounds__(256) void transpose_cvt(
    const float* __restrict__ in, unsigned short* __restrict__ out, int R, int Cd)
{
  __shared__ __align__(16) unsigned short tile[64 * 72];
  const int r0 = blockIdx.y * 64, c0 = blockIdx.x * 64;
  const int tid = threadIdx.x;
#pragma unroll
  for (int r = 0; r < 2; ++r) {
    const int elem = r * 2048 + tid * 8;
    const int ii = elem >> 6, jj = elem & 63;
    const float* p = in + (size_t)(r0 + ii) * Cd + c0 + jj;
    f32x4 a = *(const f32x4*)p, b = *(const f32x4*)(p + 4);
    short8 v;
    ((unsigned short*)&v)[0] = f2bf(a[0]); ((unsigned short*)&v)[1] = f2bf(a[1]);
    ((unsigned short*)&v)[2] = f2bf(a[2]); ((unsigned short*)&v)[3] = f2bf(a[3]);
    ((unsigned short*)&v)[4] = f2bf(b[0]); ((unsigned short*)&v)[5] = f2bf(b[1]);
    ((unsigned short*)&v)[6] = f2bf(b[2]); ((unsigned short*)&v)[7] = f2bf(b[3]);
    *(short8*)&tile[ii * 72 + jj] = v;
  }
  __syncthreads();
#pragma unroll
  for (int r = 0; r < 2; ++r) {
    const int elem = r * 2048 + tid * 8;
    const int jj = elem >> 6, ii0 = elem & 63;
    short8 v;
#pragma unroll
    for (int e = 0; e < 8; ++e) ((unsigned short*)&v)[e] = tile[(ii0 + e) * 72 + jj];
    *(short8*)&out[(size_t)(c0 + jj) * R + r0 + ii0] = v;
  }
}

// ---------------- GEMM (m97 structure), 128x128 tile ----------------
// MODE 0 (QKV): gn<1024 -> Q*SCL bf16; 1024..2047 -> K bf16; >=2048 -> Vt transposed
//   (V stores PACKED: the 4 accumulator g-values are consecutive in t -> one 8-B
//    store/lane instead of 4x 2-B scatter: 4x fewer transactions, 16x fewer insts).
// MODE 1 (proj): C fp32.
template <int MODE>
__global__ __launch_bounds__(256) void gemm_bt(
    const unsigned short* __restrict__ A,
    const unsigned short* __restrict__ Bt,
    const float* __restrict__ bias,
    void* __restrict__ Cp, unsigned short* __restrict__ Vt,
    int M, int N, int K, int lda)
{
  __shared__ __align__(16) unsigned short sA[128 * 32];
  __shared__ __align__(16) unsigned short sB[128 * 32];
  const int tid = threadIdx.x;
  const int w = tid >> 6, l = tid & 63, ln = l & 15, quad = l >> 4;
  const int wm = w >> 1, wn = w & 1;
  const int m0 = blockIdx.y * 128, n0 = blockIdx.x * 128;
  f32x4 acc[4][4] = {};

  for (int k0 = 0; k0 < K; k0 += 32) {
    __syncthreads();
#pragma unroll
    for (int r = 0; r < 2; ++r) {
      const int elem = r * 2048 + tid * 8;
      const int ar = elem >> 5, ac = elem & 31;
      async16(A  + (size_t)(m0 + ar) * lda + k0 + ac, sA + r * 2048 + w * 512);
      async16(Bt + (size_t)(n0 + ar) * K   + k0 + ac, sB + r * 2048 + w * 512);
    }
    __syncthreads();

    bf16x8 af[4], bfr[4];
#pragma unroll
    for (int i = 0; i < 4; i++)
      af[i] = *(const bf16x8*)&sA[(wm * 64 + i * 16 + ln) * 32 + quad * 8];
#pragma unroll
    for (int j = 0; j < 4; j++)
      bfr[j] = *(const bf16x8*)&sB[(wn * 64 + j * 16 + ln) * 32 + quad * 8];
#pragma unroll
    for (int i = 0; i < 4; i++)
#pragma unroll
      for (int j = 0; j < 4; j++)
        acc[i][j] = __builtin_amdgcn_mfma_f32_16x16x32_bf16(af[i], bfr[j], acc[i][j], 0, 0, 0);
  }

  float bj[4];
#pragma unroll
  for (int j = 0; j < 4; j++) bj[j] = bias[n0 + wn * 64 + j * 16 + ln];

#pragma unroll
  for (int i = 0; i < 4; i++) {
#pragma unroll
    for (int j = 0; j < 4; j++) {
      const int gn = n0 + wn * 64 + j * 16 + ln;
      if (MODE == 0 && gn >= 2048) {                 // V: pack g-quad -> one 8B store
        const int hh = (gn >> 6) & 15, dd = gn & 63;
        const int gm0 = m0 + wm * 64 + i * 16 + quad * 4;
        const int bb = gm0 >> 11, t0 = gm0 & 2047;   // g-quad never crosses batch
        sh4 rv;
#pragma unroll
        for (int g = 0; g < 4; ++g)
          ((unsigned short*)&rv)[g] = f2bf(acc[i][j][g] + bj[j]);
        *(sh4*)&Vt[((size_t)((bb * HH + hh) * DD + dd)) * TT + t0] = rv;
      } else {
#pragma unroll
        for (int g = 0; g < 4; ++g) {
          const int gm = m0 + wm * 64 + i * 16 + quad * 4 + g;
          float v = acc[i][j][g] + bj[j];
          if (MODE == 0) {
            if (gn < 1024) v *= SCL;   // fold softmax scale into Q (pre-round: free)
            ((unsigned short*)Cp)[(size_t)gm * 2048 + gn] = f2bf(v);
          } else {
            ((float*)Cp)[(size_t)gm * N + gn] = v;
          }
        }
      }
    }
  }
}

// ---------------- GEMM, 128x64 tile (for N=1024 proj: 512 blocks = 2/CU) ----------------
// Same m97 inner structure; each of 4 waves owns a 64x32 sub-tile (acc[4][2]).
// Rationale: 128x128 tiling gives N=1024 only 256 blocks = 1 block/CU = 1 wave/SIMD
// (round-1-proven occupancy starvation). 128x64 doubles co-residency.
__global__ __launch_bounds__(256) void gemm_n64(
    const unsigned short* __restrict__ A,
    const unsigned short* __restrict__ Bt,
    const float* __restrict__ bias,
    float* __restrict__ Cp, int M, int N, int K, int lda)
{
  __shared__ __align__(16) unsigned short sA[128 * 32];
  __shared__ __align__(16) unsigned short sB[64 * 32];
  const int tid = threadIdx.x;
  const int w = tid >> 6, l = tid & 63, ln = l & 15, quad = l >> 4;
  const int wm = w >> 1, wn = w & 1;
  const int m0 = blockIdx.y * 128, n0 = blockIdx.x * 64;
  f32x4 acc[4][2] = {};

  for (int k0 = 0; k0 < K; k0 += 32) {
    __syncthreads();
#pragma unroll
    for (int r = 0; r < 2; ++r) {
      const int elem = r * 2048 + tid * 8;
      const int ar = elem >> 5, ac = elem & 31;
      async16(A + (size_t)(m0 + ar) * lda + k0 + ac, sA + r * 2048 + w * 512);
    }
    {
      const int elem = tid * 8;
      const int ar = elem >> 5, ac = elem & 31;
      async16(Bt + (size_t)(n0 + ar) * K + k0 + ac, sB + w * 512);
    }
    __syncthreads();

    bf16x8 af[4], bfr[2];
#pragma unroll
    for (int i = 0; i < 4; i++)
      af[i] = *(const bf16x8*)&sA[(wm * 64 + i * 16 + ln) * 32 + quad * 8];
#pragma unroll
    for (int j = 0; j < 2; j++)
      bfr[j] = *(const bf16x8*)&sB[(wn * 32 + j * 16 + ln) * 32 + quad * 8];
#pragma unroll
    for (int i = 0; i < 4; i++)
#pragma unroll
      for (int j = 0; j < 2; j++)
        acc[i][j] = __builtin_amdgcn_mfma_f32_16x16x32_bf16(af[i], bfr[j], acc[i][j], 0, 0, 0);
  }

  float bj[2];
#pragma unroll
  for (int j = 0; j < 2; j++) bj[j] = bias[n0 + wn * 32 + j * 16 + ln];

#pragma unroll
  for (int i = 0; i < 4; i++)
#pragma unroll
    for (int g = 0; g < 4; ++g) {
      const int gm = m0 + wm * 64 + i * 16 + quad * 4 + g;
#pragma unroll
      for (int j = 0; j < 2; j++) {
        const int gn = n0 + wn * 32 + j * 16 + ln;
        Cp[(size_t)gm * N + gn] = acc[i][j][g] + bj[j];
      }
    }
}

// ---------------- Flash attention (causal), D=64, 128-row q-tiles ----------------
// (round-2 best-measured version, 54.9us, verbatim)
// 512 thr = 8 waves; wave w owns q rows qt*128+w*16..+15. Grid (8 pairs, 32 bh),
// block runs {p, 15-p} -> uniform 34 kb-iters, 256 blocks = 1/CU.
// PIPELINED: PV lags QK by one tile (iterations independent under STATIC softmax,
// P(kb) kept in regs across the barrier). vt is a rotating TRIPLE buffer. l via
// in-lane fp32 adds + epilogue shfl_xor reduce.
__global__ __launch_bounds__(512) void attn128(
    unsigned short* __restrict__ QK, const unsigned short* __restrict__ Vt)
{
  __shared__ __align__(16) unsigned short kt[2][64 * 72];   // [key][d]
  __shared__ __align__(16) unsigned short vt[3][64 * 72];   // [d][key] rotating
  __shared__ __align__(16) unsigned short pt[8][16 * 72];   // per-wave P
  const int pair = blockIdx.x, bh = blockIdx.y;
  const int b = bh >> 4, h = bh & 15;
  const int tid = threadIdx.x, w = tid >> 6, l = tid & 63, ln = l & 15, quad = l >> 4;
  unsigned short*       Qp = QK + (size_t)b * TT * 2048 + h * DD;
  const unsigned short* Kp = QK + (size_t)b * TT * 2048 + CC + h * DD;
  const unsigned short* Vh = Vt + (size_t)bh * DD * TT;
  const int si = tid >> 3, so = (tid & 7) * 8;              // 512 thr cover 64x64 once

  for (int ph = 0; ph < 2; ++ph) {
    const int qt = ph ? 15 - pair : pair;
    const int qrow = qt * 128 + w * 16 + ln;
    bf16x8 qf0 = *(const bf16x8*)&Qp[(size_t)qrow * 2048 + quad * 8];
    bf16x8 qf1 = *(const bf16x8*)&Qp[(size_t)qrow * 2048 + 32 + quad * 8];

    f32x4 oacc[4] = {};
    f32x4 lacc = {};
    bf16x8 pf0 = {}, pf1 = {};
    const int qg = qt * 128 + w * 16 + quad * 4;
    const int wfirst = qt * 128 + w * 16, wlast = wfirst + 15;
    const int kbmax = 2 * qt + 1;
    int vm1 = 2, v0 = 0, vp1 = 1;                           // (kb-1,kb,kb+1) % 3

    __syncthreads();                                        // prior phase drain done
    *(short8*)&kt[0][si * 72 + so] = *(const short8*)&Kp[(size_t)si * 2048 + so];
    *(short8*)&vt[0][si * 72 + so] = *(const short8*)&Vh[(size_t)si * TT + so];
    __syncthreads();                                        // buf0 visible

    for (int kb = 0; kb <= kbmax; ++kb) {
      const int ck = kb & 1;
      short8 pk, pv;
      if (kb < kbmax) {                                     // prefetch kb+1 -> regs
        pk = *(const short8*)&Kp[(size_t)((kb + 1) * 64 + si) * 2048 + so];
        pv = *(const short8*)&Vh[(size_t)si * TT + (kb + 1) * 64 + so];
      }
      const bool qk_act = (kb * 64 <= wlast);               // wave-uniform
      f32x4 sacc[4] = {};
      if (qk_act) {                                         // QK(kb)
#pragma unroll
        for (int n = 0; n < 4; n++) {
          bf16x8 bk0 = *(const bf16x8*)&kt[ck][(n * 16 + ln) * 72 + quad * 8];
          bf16x8 bk1 = *(const bf16x8*)&kt[ck][(n * 16 + ln) * 72 + 32 + quad * 8];
          sacc[n] = __builtin_amdgcn_mfma_f32_16x16x32_bf16(qf0, bk0, sacc[n], 0, 0, 0);
          sacc[n] = __builtin_amdgcn_mfma_f32_16x16x32_bf16(qf1, bk1, sacc[n], 0, 0, 0);
        }
      }
      if (kb > 0 && (kb - 1) * 64 <= wlast) {               // PV(kb-1): independent,
        const unsigned short* vp = vt[vm1];                 // issues under exp2 latency
#pragma unroll
        for (int n = 0; n < 4; n++) {
          bf16x8 bv0 = *(const bf16x8*)&vp[(n * 16 + ln) * 72 + quad * 8];
          bf16x8 bv1 = *(const bf16x8*)&vp[(n * 16 + ln) * 72 + 32 + quad * 8];
          oacc[n] = __builtin_amdgcn_mfma_f32_16x16x32_bf16(pf0, bv0, oacc[n], 0, 0, 0);
          oacc[n] = __builtin_amdgcn_mfma_f32_16x16x32_bf16(pf1, bv1, oacc[n], 0, 0, 0);
        }
      }
      if (qk_act) {
        if (kb * 64 + 63 > wfirst) {                        // diagonal: mask needed
#pragma unroll
          for (int n = 0; n < 4; n++) {
            const int keyg = kb * 64 + n * 16 + ln;
#pragma unroll
            for (int g = 0; g < 4; ++g)
              if (keyg > qg + g) sacc[n][g] = NEGBIG;
          }
        }
        float pe[4][4];
#pragma unroll
        for (int n = 0; n < 4; n++)
#pragma unroll
          for (int g = 0; g < 4; ++g) pe[n][g] = exp2f(sacc[n][g]);
#pragma unroll
        for (int g = 0; g < 4; ++g)                         // l: fp32, pre-pack
          lacc[g] += (pe[0][g] + pe[1][g]) + (pe[2][g] + pe[3][g]);
#pragma unroll
        for (int n = 0; n < 4; n++)
#pragma unroll
          for (int g = 0; g < 4; ++g)
            pt[w][(quad * 4 + g) * 72 + n * 16 + ln] = f2bf_tr(pe[n][g]);
        __builtin_amdgcn_wave_barrier();                    // order pt write->read
        pf0 = *(const bf16x8*)&pt[w][ln * 72 + quad * 8];   // P(kb) -> regs for kb+1
        pf1 = *(const bf16x8*)&pt[w][ln * 72 + 32 + quad * 8];
      }
      if (kb < kbmax) {                                     // stage kb+1
        *(short8*)&kt[1 - ck][si * 72 + so] = pk;
        *(short8*)&vt[vp1][si * 72 + so] = pv;
      }
      __syncthreads();                                      // one barrier per iter
      const int t_ = vm1; vm1 = v0; v0 = vp1; vp1 = t_;     // rotate V buffers
    }
    // drain: PV(kbmax) for waves whose last tile is kbmax (upper half)
    if (kbmax * 64 <= wlast) {
      const unsigned short* vp = vt[vm1];                   // vm1 == kbmax % 3
#pragma unroll
      for (int n = 0; n < 4; n++) {
        bf16x8 bv0 = *(const bf16x8*)&vp[(n * 16 + ln) * 72 + quad * 8];
        bf16x8 bv1 = *(const bf16x8*)&vp[(n * 16 + ln) * 72 + 32 + quad * 8];
        oacc[n] = __builtin_amdgcn_mfma_f32_16x16x32_bf16(pf0, bv0, oacc[n], 0, 0, 0);
        oacc[n] = __builtin_amdgcn_mfma_f32_16x16x32_bf16(pf1, bv1, oacc[n], 0, 0, 0);
      }
    }
    // epilogue: reduce l across the 16-lane quad group, normalize, store
#pragma unroll
    for (int g = 0; g < 4; ++g) {
      float s = lacc[g];
      s += __shfl_xor(s, 1);
      s += __shfl_xor(s, 2);
      s += __shfl_xor(s, 4);
      s += __shfl_xor(s, 8);
      const float inv = 1.0f / s;
      const int t = qg + g;
#pragma unroll
      for (int n = 0; n < 4; n++)
        Qp[(size_t)t * 2048 + n * 16 + ln] = f2bf(oacc[n][g] * inv);
    }
  }
}

extern "C" void kernel_launch(void* const* d_in, const int* in_sizes, int n_in,
                              void* d_out, int out_size, void* d_ws, size_t ws_size,
                              hipStream_t stream)
{
  (void)in_sizes; (void)n_in; (void)out_size; (void)ws_size;
  const float* x     = (const float*)d_in[0];   // [B,T,C] fp32
  const float* Wqkv  = (const float*)d_in[1];   // [C,3C]
  const float* bqkv  = (const float*)d_in[2];   // [3C]
  const float* Wproj = (const float*)d_in[3];   // [C,C]
  const float* bproj = (const float*)d_in[4];   // [C]

  unsigned short* QK     = (unsigned short*)d_ws;            // [4096][2048] bf16, 16 MB
  unsigned short* WqkvT  = QK + (size_t)4096 * 2048;         // [3072][1024] bf16, 6 MB
  unsigned short* WprojT = WqkvT;                            // aliases (after GEMM1)
  unsigned short* Vt = (unsigned short*)d_out;               // scratch in d_out, 8 MB
  unsigned short* xb = Vt + (size_t)32 * 64 * 2048;          // scratch in d_out, 8 MB

  cvt_bf16<<<dim3(4096 * 1024 / 8 / 256), 256, 0, stream>>>(x, xb, 4096 * 1024 / 8);
  transpose_cvt<<<dim3(C3 / 64, CC / 64), 256, 0, stream>>>(Wqkv, WqkvT, CC, C3);
  gemm_bt<0><<<dim3(C3 / 128, 4096 / 128), 256, 0, stream>>>(
      xb, WqkvT, bqkv, QK, Vt, 4096, C3, CC, CC);
  transpose_cvt<<<dim3(CC / 64, CC / 64), 256, 0, stream>>>(Wproj, WprojT, CC, CC);
  attn128<<<dim3(8, 2 * HH), 512, 0, stream>>>(QK, Vt);
  gemm_n64<<<dim3(CC / 64, 4096 / 128), 256, 0, stream>>>(
      QK, WprojT, bproj, (float*)d_out, 4096, CC, CC, 2048);
}